// Round 12
// baseline (201.685 us; speedup 1.0000x reference)
//
#include <hip/hip_runtime.h>
#include <math.h>

#define HD 56
#define WD 56
#define CD 64
#define PLANE 3136   // 56*56

typedef _Float16 f16x8 __attribute__((ext_vector_type(8)));
typedef _Float16 f16x4 __attribute__((ext_vector_type(4)));
typedef _Float16 f16x2 __attribute__((ext_vector_type(2)));
typedef float    f32x4 __attribute__((ext_vector_type(4)));

// ---- weight transpose + f16 (6 jobs) ----
__global__ __launch_bounds__(256) void wtrans_k(
    const float* __restrict__ w1, const float* __restrict__ w3, const float* __restrict__ w2,
    const float* __restrict__ ow1, const float* __restrict__ ow3, const float* __restrict__ ow2,
    _Float16* __restrict__ t1, _Float16* __restrict__ t3, _Float16* __restrict__ t2,
    _Float16* __restrict__ owF, _Float16* __restrict__ owT2)
{
    int y = blockIdx.y;
    if (y == 0 || y == 1 || y == 2) {
        const float* src = (y == 0) ? w1 : (y == 1) ? w3 : w2;
        _Float16* dst    = (y == 0) ? t1 : (y == 1) ? t3 : t2;
        int K2 = (y == 1) ? 25 : 9;
        int total = 64 * 64 * K2;
        for (int idx = blockIdx.x * 256 + threadIdx.x; idx < total; idx += gridDim.x * 256) {
            int k = idx >> 12;
            int o = (idx >> 6) & 63;
            int c = idx & 63;
            dst[idx] = (_Float16)src[(o * 64 + c) * K2 + k];
        }
    } else if (y == 3) {
        int total = 9 * 32 * 64;
        for (int idx = blockIdx.x * 256 + threadIdx.x; idx < total; idx += gridDim.x * 256) {
            int k = idx >> 11;
            int o = (idx >> 6) & 31;
            int c = idx & 63;
            owF[k * 6144 + o * 64 + c] = (o < 18) ? (_Float16)ow1[(o * 64 + c) * 9 + k] : (_Float16)0.f;
        }
    } else if (y == 4) {
        int total = 9 * 64 * 64;
        for (int idx = blockIdx.x * 256 + threadIdx.x; idx < total; idx += gridDim.x * 256) {
            int k = idx >> 12;
            int o = (idx >> 6) & 63;
            int c = idx & 63;
            owF[k * 6144 + (32 + o) * 64 + c] = (o < 50) ? (_Float16)ow3[(o * 64 + c) * 9 + k] : (_Float16)0.f;
        }
    } else {
        int total = 9 * 32 * 64;
        for (int idx = blockIdx.x * 256 + threadIdx.x; idx < total; idx += gridDim.x * 256) {
            int k = idx >> 11;
            int o = (idx >> 6) & 31;
            int c = idx & 63;
            owT2[k * 2048 + o * 64 + c] = (o < 18) ? (_Float16)ow2[(o * 64 + c) * 9 + k] : (_Float16)0.f;
        }
    }
}

// ---- channel transpose to f16: dst[b][pix][c] = (f16)src[b][c][pix] ----
__global__ __launch_bounds__(256) void xt_k(const float* __restrict__ src, _Float16* __restrict__ dst)
{
    int b  = blockIdx.y;
    int px = blockIdx.x * 64 + (threadIdx.x & 63);
    int cg = threadIdx.x >> 6;
    const float* s = src + (size_t)b * CD * PLANE + px;
    f16x8 lo, hi;
#pragma unroll
    for (int i = 0; i < 8; ++i) lo[i] = (_Float16)s[(cg * 16 + i) * PLANE];
#pragma unroll
    for (int i = 0; i < 8; ++i) hi[i] = (_Float16)s[(cg * 16 + 8 + i) * PLANE];
    _Float16* d = dst + ((size_t)b * PLANE + px) * 64 + cg * 16;
    *(f16x8*)d = lo;
    *(f16x8*)(d + 8) = hi;
}

// ---------------- offset conv (f16 MFMA) fused with tapprep ----------------
// Same mapping as round 11, plus: neighbor loads hoisted up front, A-frag depth-1 stages.
template<int NTILES, int OP>
__device__ inline void af_load(const _Float16* __restrict__ ow, int k, int off, f16x8* s) {
    const _Float16* wk = ow + k * (OP * 64);
#pragma unroll
    for (int t = 0; t < NTILES; ++t) s[t] = *(const f16x8*)(wk + (t * 16) * 64 + off);
}

template<int FUSED>
__global__ __launch_bounds__(256) void offc_k(
    const _Float16* __restrict__ src,     // [b][pix][64]
    const _Float16* __restrict__ ow,      // [9][OP][64]
    const float* __restrict__ biasA, const float* __restrict__ biasB,
    uint4* __restrict__ tbl)
{
    constexpr int NTILES = FUSED ? 6 : 2;
    constexpr int OP     = FUSED ? 96 : 32;
    constexpr int NTT    = FUSED ? 34 : 9;
    __shared__ float red[4][NTILES * 4 * 64];

    int tid = threadIdx.x;
    int bid = blockIdx.x;
    int b    = bid & 7;
    int tile = bid >> 3;
    int l = tid & 63;
    int n = l & 15;
    int g = l >> 4;
    int w = tid >> 6;
    int tg = w >> 1;
    int pix = tile * 16 + n;
    int ho = pix / WD, wo = pix - ho * WD;
    int ckoff = (w & 1) * 32 + g * 8;
    int afo = n * 64 + ckoff;
    const _Float16* sp = src + ((size_t)b * PLANE + pix) * 64 + ckoff;

    f32x4 acc[NTILES];
#pragma unroll
    for (int t = 0; t < NTILES; ++t) acc[t] = (f32x4){0.f, 0.f, 0.f, 0.f};

#define NB(K, D) { int ky_=(K)/3-1, kx_=(K)%3-1; int yn_=ho+ky_, xn_=wo+kx_;       \
    f16x8 z_ = {(_Float16)0,(_Float16)0,(_Float16)0,(_Float16)0,                   \
                (_Float16)0,(_Float16)0,(_Float16)0,(_Float16)0};                  \
    D = z_;                                                                        \
    if ((unsigned)yn_ < (unsigned)HD && (unsigned)xn_ < (unsigned)WD)              \
        D = *(const f16x8*)(sp + (ky_ * WD + kx_) * 64); }

#define MFMAS(S, NBV) { _Pragma("unroll")                                          \
    for (int t = 0; t < NTILES; ++t)                                               \
        acc[t] = __builtin_amdgcn_mfma_f32_16x16x32_f16((S)[t], NBV, acc[t], 0, 0, 0); }

    f16x8 sA[NTILES], sB[NTILES];
    if (tg == 0) {
        f16x8 nb0, nb1, nb2, nb3, nb4;
        NB(0, nb0) NB(1, nb1) NB(2, nb2) NB(3, nb3) NB(4, nb4)
        af_load<NTILES, OP>(ow, 0, afo, sA);
        af_load<NTILES, OP>(ow, 1, afo, sB); MFMAS(sA, nb0)
        af_load<NTILES, OP>(ow, 2, afo, sA); MFMAS(sB, nb1)
        af_load<NTILES, OP>(ow, 3, afo, sB); MFMAS(sA, nb2)
        af_load<NTILES, OP>(ow, 4, afo, sA); MFMAS(sB, nb3)
        MFMAS(sA, nb4)
    } else {
        f16x8 nb0, nb1, nb2, nb3;
        NB(5, nb0) NB(6, nb1) NB(7, nb2) NB(8, nb3)
        af_load<NTILES, OP>(ow, 5, afo, sA);
        af_load<NTILES, OP>(ow, 6, afo, sB); MFMAS(sA, nb0)
        af_load<NTILES, OP>(ow, 7, afo, sA); MFMAS(sB, nb1)
        af_load<NTILES, OP>(ow, 8, afo, sB); MFMAS(sA, nb2)
        MFMAS(sB, nb3)
    }
#undef NB
#undef MFMAS

    // 4-way reduce; then wave w handles tiles {w, w+4}
#pragma unroll
    for (int t = 0; t < NTILES; ++t)
#pragma unroll
        for (int rr = 0; rr < 4; ++rr)
            red[w][(t * 4 + rr) * 64 + l] = acc[t][rr];
    __syncthreads();

#pragma unroll
    for (int tt = 0; tt < (NTILES + 3) / 4; ++tt) {
        int t = w + tt * 4;
        if (t < NTILES) {
            float v[4];
#pragma unroll
            for (int rr = 0; rr < 4; ++rr) {
                int ia = (t * 4 + rr) * 64 + l;
                v[rr] = red[0][ia] + red[1][ia] + red[2][ia] + red[3][ia];
            }
            int obase = t * 16 + g * 4;
            bool isB = FUSED && (t >= 2);
            int oc0 = isB ? (obase - 32) : obase;
            const float* bp = isB ? biasB : biasA;
#pragma unroll
            for (int pp = 0; pp < 2; ++pp) {
                int oce = oc0 + pp * 2;
                int kl  = oce >> 1;
                int kmax = isB ? 25 : 9;
                if (kl < kmax) {
                    float dy = v[pp * 2]     + bp[oce];
                    float dx = v[pp * 2 + 1] + bp[oce + 1];
                    int by, bx;
                    if (isB) { int q = kl / 5; by = q * 2 - 4; bx = (kl - q * 5) * 2 - 4; }
                    else     { int q = kl / 3; by = q * 2 - 2; bx = (kl - q * 3) * 2 - 2; }
                    float py = dy + (float)(by + ho);
                    float px = dx + (float)(bx + wo);
                    float fy = floorf(py), fx = floorf(px);
                    float wy1 = py - fy, wx1 = px - fx;
                    float wy0 = 1.f - wy1, wx0 = 1.f - wx1;
                    int y0 = (int)fy, x0 = (int)fx;
                    int y1 = y0 + 1, x1 = x0 + 1;
                    float vy0 = (y0 >= 0 && y0 < HD) ? 1.f : 0.f;
                    float vy1 = (y1 >= 0 && y1 < HD) ? 1.f : 0.f;
                    float vx0 = (x0 >= 0 && x0 < WD) ? 1.f : 0.f;
                    float vx1 = (x1 >= 0 && x1 < WD) ? 1.f : 0.f;
                    int cy0 = min(max(y0, 0), HD - 1), cy1 = min(max(y1, 0), HD - 1);
                    int cx0 = min(max(x0, 0), WD - 1), cx1 = min(max(x1, 0), WD - 1);
                    unsigned i00 = (unsigned)(cy0 * WD + cx0), i01 = (unsigned)(cy0 * WD + cx1);
                    unsigned i10 = (unsigned)(cy1 * WD + cx0), i11 = (unsigned)(cy1 * WD + cx1);
                    f16x2 wl = {(_Float16)(wy0 * wx0 * vy0 * vx0), (_Float16)(wy0 * wx1 * vy0 * vx1)};
                    f16x2 wh = {(_Float16)(wy1 * wx0 * vy1 * vx0), (_Float16)(wy1 * wx1 * vy1 * vx1)};
                    uint4 e;
                    e.x = i00 | (i01 << 16);
                    e.y = i10 | (i11 << 16);
                    e.z = __builtin_bit_cast(unsigned int, wl);
                    e.w = __builtin_bit_cast(unsigned int, wh);
                    int gtap = isB ? (9 + kl) : kl;
                    tbl[((size_t)(b * NTT + gtap)) * PLANE + pix] = e;
                }
            }
        }
    }
}

// ---------------- deformable conv + BN: depth-2 pipeline, 8-wave tap/K split ----------------
// MERGED==1: 512 thr = 8 waves (kh x 4 tap-groups 9/9/8/8); outh f16 [pix][c].
// MERGED==0: 256 thr = 4 waves (kh x 2 tap-groups 5/4);  out fp32 NCHW = relu(bn+addsrc).
// Each wave: ONE acc set (A if tg==0 or !MERGED, else B). Rotation-free double-buffered
// register stages s0/s1 (parity by unrolled pair loop): tap t's 9 loads issued 2 steps early.
template<int MERGED>
__global__ __launch_bounds__(MERGED ? 512 : 256) void dconv_k(
    const _Float16* __restrict__ xt,      // [b][pix][64] f16
    const uint4* __restrict__ tbl,        // [b][NT][PLANE]
    const _Float16* __restrict__ wTA, const _Float16* __restrict__ wTB, // [k][o][c]
    const float* __restrict__ gA, const float* __restrict__ bA,
    const float* __restrict__ mA, const float* __restrict__ vA,
    const float* __restrict__ gB, const float* __restrict__ bB,
    const float* __restrict__ mB, const float* __restrict__ vB,
    const float* __restrict__ addsrc, float* __restrict__ out,
    _Float16* __restrict__ outh)
{
    constexpr int NT = MERGED ? 34 : 9;
    constexpr int NW = MERGED ? 8 : 4;
    __shared__ float red[NW - 1][16 * 64];

    int tid = threadIdx.x;
    int bid = blockIdx.x;
    int b    = bid & 7;
    int tile = bid >> 3;
    int l   = tid & 63;
    int n   = l & 15;
    int g   = l >> 4;
    int w   = tid >> 6;
    int kh  = w & 1;
    int tg  = w >> 1;
    int pix = tile * 16 + n;
    int ckoff = kh * 32 + g * 8;

    int base, cnt;
    if (MERGED) { base = (tg == 0) ? 0 : (tg == 1) ? 9 : (tg == 2) ? 18 : 26; cnt = (tg < 2) ? 9 : 8; }
    else        { base = tg ? 5 : 0; cnt = tg ? 4 : 5; }
    int lastT = base + cnt - 1;

    const _Float16* xp = xt + (size_t)b * PLANE * 64 + ckoff;
    const uint4*    tp = tbl + (size_t)b * NT * PLANE + pix;
    int afoff = n * 64 + ckoff;

    f32x4 acc[4];
#pragma unroll
    for (int ot = 0; ot < 4; ++ot) acc[ot] = (f32x4){0.f, 0.f, 0.f, 0.f};

#define DECL_STG(S) f16x8 S##c0, S##c1, S##c2, S##c3, S##a0, S##a1, S##a2, S##a3; \
                    unsigned S##wz, S##ww
    DECL_STG(s0);
    DECL_STG(s1);
#undef DECL_STG

#define ISSUE(S, E, T) {                                                      \
    unsigned i00_ = (E).x & 0xffffu, i01_ = (E).x >> 16;                      \
    unsigned i10_ = (E).y & 0xffffu, i11_ = (E).y >> 16;                      \
    S##wz = (E).z; S##ww = (E).w;                                             \
    S##c0 = *(const f16x8*)(xp + i00_ * 64);                                  \
    S##c1 = *(const f16x8*)(xp + i01_ * 64);                                  \
    S##c2 = *(const f16x8*)(xp + i10_ * 64);                                  \
    S##c3 = *(const f16x8*)(xp + i11_ * 64);                                  \
    const _Float16* wk_ = (!MERGED || (T) < 9) ? (wTA + (T) * 4096)           \
                                               : (wTB + ((T) - 9) * 4096);    \
    S##a0 = *(const f16x8*)(wk_ + afoff);                                     \
    S##a1 = *(const f16x8*)(wk_ + afoff + 1024);                              \
    S##a2 = *(const f16x8*)(wk_ + afoff + 2048);                              \
    S##a3 = *(const f16x8*)(wk_ + afoff + 3072); }

#define CONSUME(S) {                                                          \
    f16x2 wl_ = __builtin_bit_cast(f16x2, S##wz);                             \
    f16x2 wh_ = __builtin_bit_cast(f16x2, S##ww);                             \
    f16x8 bf_ = S##c0 * wl_.x + S##c1 * wl_.y + S##c2 * wh_.x + S##c3 * wh_.y;\
    acc[0] = __builtin_amdgcn_mfma_f32_16x16x32_f16(S##a0, bf_, acc[0], 0, 0, 0); \
    acc[1] = __builtin_amdgcn_mfma_f32_16x16x32_f16(S##a1, bf_, acc[1], 0, 0, 0); \
    acc[2] = __builtin_amdgcn_mfma_f32_16x16x32_f16(S##a2, bf_, acc[2], 0, 0, 0); \
    acc[3] = __builtin_amdgcn_mfma_f32_16x16x32_f16(S##a3, bf_, acc[3], 0, 0, 0); }

    // ---- prologue: taps base, base+1 into stages; entries base+2, base+3 prefetched ----
    {
        uint4 e0 = tp[base * PLANE];
        uint4 e1 = tp[(base + 1) * PLANE];
        ISSUE(s0, e0, base)
        ISSUE(s1, e1, base + 1)
    }
    uint4 E0 = tp[min(base + 2, lastT) * PLANE];
    uint4 E1 = tp[min(base + 3, lastT) * PLANE];

    int j = 0;
#pragma unroll 1
    for (; j + 1 < cnt; j += 2) {
        CONSUME(s0)
        if (j + 2 < cnt) {
            ISSUE(s0, E0, base + j + 2)
            E0 = tp[min(base + j + 4, lastT) * PLANE];
        }
        CONSUME(s1)
        if (j + 3 < cnt) {
            ISSUE(s1, E1, base + j + 3)
            E1 = tp[min(base + j + 5, lastT) * PLANE];
        }
    }
    if (j < cnt) CONSUME(s0)
#undef ISSUE
#undef CONSUME

    // reduce: waves 1..NW-1 write partials; wave 0 sums + epilogue
    if (w > 0) {
#pragma unroll
        for (int ot = 0; ot < 4; ++ot)
#pragma unroll
            for (int rr = 0; rr < 4; ++rr)
                red[w - 1][(ot * 4 + rr) * 64 + l] = acc[ot][rr];
    }
    __syncthreads();
    if (w == 0) {
#pragma unroll
        for (int ot = 0; ot < 4; ++ot) {
            float r[4];
#pragma unroll
            for (int rr = 0; rr < 4; ++rr) {
                int ia = (ot * 4 + rr) * 64 + l;
                int o = ot * 16 + g * 4 + rr;
                if (MERGED) {
                    float sumA = acc[ot][rr] + red[0][ia];
                    float sumB = red[1][ia] + red[2][ia] + red[3][ia]
                               + red[4][ia] + red[5][ia] + red[6][ia];
                    float ivA = gA[o] * (1.f / sqrtf(vA[o] + 1e-5f));
                    float shA = bA[o] - mA[o] * ivA;
                    float ivB = gB[o] * (1.f / sqrtf(vB[o] + 1e-5f));
                    float shB = bB[o] - mB[o] * ivB;
                    r[rr] = fmaxf(sumA * ivA + shA, 0.f) + fmaxf(sumB * ivB + shB, 0.f);
                } else {
                    float s = acc[ot][rr] + red[0][ia] + red[1][ia] + red[2][ia];
                    float iv = gA[o] * (1.f / sqrtf(vA[o] + 1e-5f));
                    float sh = bA[o] - mA[o] * iv;
                    size_t oidx = (size_t)(b * 64 + o) * PLANE + pix;
                    out[oidx] = fmaxf(s * iv + sh + addsrc[oidx], 0.f);
                }
            }
            if (MERGED) {
                f16x4 hv = {(_Float16)r[0], (_Float16)r[1], (_Float16)r[2], (_Float16)r[3]};
                *(f16x4*)(outh + ((size_t)b * PLANE + pix) * 64 + ot * 16 + g * 4) = hv;
            }
        }
    }
}

extern "C" void kernel_launch(void* const* d_in, const int* in_sizes, int n_in,
                              void* d_out, int out_size, void* d_ws, size_t ws_size,
                              hipStream_t stream) {
    const float* x   = (const float*)d_in[0];
    const float* ow1 = (const float*)d_in[1];
    const float* ob1 = (const float*)d_in[2];
    const float* ow3 = (const float*)d_in[3];
    const float* ob3 = (const float*)d_in[4];
    const float* ow2 = (const float*)d_in[5];
    const float* ob2 = (const float*)d_in[6];
    const float* w1  = (const float*)d_in[7];
    const float* w3  = (const float*)d_in[8];
    const float* w2  = (const float*)d_in[9];
    const float* g1  = (const float*)d_in[10];
    const float* b1  = (const float*)d_in[11];
    const float* m1  = (const float*)d_in[12];
    const float* v1  = (const float*)d_in[13];
    const float* g3  = (const float*)d_in[14];
    const float* b3  = (const float*)d_in[15];
    const float* m3  = (const float*)d_in[16];
    const float* v3  = (const float*)d_in[17];
    const float* g2  = (const float*)d_in[18];
    const float* b2  = (const float*)d_in[19];
    const float* m2  = (const float*)d_in[20];
    const float* v2  = (const float*)d_in[21];

    float* out = (float*)d_out;
    float* ws  = (float*)d_ws;

    // ws layout (float units)
    _Float16* xth  = (_Float16*)ws;                 // 1,605,632 f16 = 802,816 fl
    _Float16* mth  = (_Float16*)(ws + 802816);      // 1,605,632 f16
    uint4*    tbl  = (uint4*)(ws + 1605632);        // 852,992 x 16B (34-tap; 9-tap reuses prefix)
    _Float16* wT1h = (_Float16*)(ws + 5017600);     // 36,864 f16
    _Float16* wT3h = wT1h + 36864;                  // 102,400 f16
    _Float16* wT2h = wT3h + 102400;                 // 36,864 f16
    _Float16* owFh = wT2h + 36864;                  // 9*96*64 = 55,296 f16
    _Float16* owT2h= owFh + 55296;                  // 9*32*64 = 18,432 f16

    wtrans_k<<<dim3(16, 6), dim3(256), 0, stream>>>(
        w1, w3, w2, ow1, ow3, ow2, wT1h, wT3h, wT2h, owFh, owT2h);
    xt_k<<<dim3(49, 8), dim3(256), 0, stream>>>(x, xth);

    offc_k<1><<<dim3(1568), dim3(256), 0, stream>>>(xth, owFh, ob1, ob3, tbl);

    dconv_k<1><<<dim3(1568), dim3(512), 0, stream>>>(
        xth, tbl, wT1h, wT3h, g1, b1, m1, v1, g3, b3, m3, v3, nullptr, nullptr, mth);

    offc_k<0><<<dim3(1568), dim3(256), 0, stream>>>(mth, owT2h, ob2, ob2, tbl);

    dconv_k<0><<<dim3(1568), dim3(256), 0, stream>>>(
        mth, tbl, wT2h, wT2h, g2, b2, m2, v2, g2, b2, m2, v2, x, out, nullptr);
}